// Round 3
// baseline (2795.114 us; speedup 1.0000x reference)
//
#include <hip/hip_runtime.h>
#include <cstdint>

#define NN 100000
#define NE 1600000

typedef __attribute__((ext_vector_type(8))) short bf16x8;
typedef __attribute__((ext_vector_type(4))) float f32x4;

static __device__ __forceinline__ short f2bf(float f) {
  union { float f; unsigned u; } v; v.f = f;
  unsigned r = (v.u + 0x7FFFu + ((v.u >> 16) & 1u)) >> 16;
  return (short)r;
}
static __device__ __forceinline__ float bf2f(unsigned short s) {
  union { unsigned u; float f; } v; v.u = ((unsigned)s) << 16;
  return v.f;
}
// pack 2 f32 -> 2 bf16 in one dword (RTNE), dst[15:0]=lo, dst[31:16]=hi
static __device__ __forceinline__ unsigned cvtpk(float lo, float hi) {
  unsigned r;
  asm("v_cvt_pk_bf16_f32 %0, %1, %2" : "=v"(r) : "v"(lo), "v"(hi));
  return r;
}

// ---------------- zero helper ----------------
__global__ void zero_k(int* __restrict__ p, int n) {
  int i = blockIdx.x * 256 + threadIdx.x;
  if (i < n) p[i] = 0;
}

// ---------------- weight pre-convert to MFMA fragment order ----------------
// W1f: [kb<32][nt<32][lane<64][j<8]  K=1024(pad 1000), N=512   (1 MB)
// W2f: [kb<16][nt<16][lane][j]       K=512, N=256              (256KB)
// Wgf: [kb<9 ][nt<8 ][lane][j]       K=288(pad 266), N=128     (72KB)
__global__ void wconv_k(const float* __restrict__ W1, const float* __restrict__ W2,
                        const float* __restrict__ Wg,
                        bf16x8* __restrict__ W1f, bf16x8* __restrict__ W2f,
                        bf16x8* __restrict__ Wgf) {
  int id = blockIdx.x * 256 + threadIdx.x;
  const int n1 = 32 * 32 * 64, n2 = 16 * 16 * 64, n3 = 9 * 8 * 64;
  if (id < n1) {
    int lane = id & 63, nt = (id >> 6) & 31, kb = id >> 11;
    int q = lane >> 4, ln = lane & 15, n = nt * 16 + ln;
    bf16x8 o;
#pragma unroll
    for (int j = 0; j < 8; ++j) {
      int k = kb * 32 + q * 8 + j;
      o[j] = (k < 1000) ? f2bf(W1[k * 512 + n]) : (short)0;
    }
    W1f[id] = o;
  } else if (id < n1 + n2) {
    int t = id - n1;
    int lane = t & 63, nt = (t >> 6) & 15, kb = t >> 10;
    int q = lane >> 4, ln = lane & 15, n = nt * 16 + ln;
    bf16x8 o;
#pragma unroll
    for (int j = 0; j < 8; ++j) {
      int k = kb * 32 + q * 8 + j;
      o[j] = f2bf(W2[k * 256 + n]);
    }
    W2f[t] = o;
  } else if (id < n1 + n2 + n3) {
    int t = id - n1 - n2;
    int lane = t & 63, nt = (t >> 6) & 7, kb = t >> 9;
    int q = lane >> 4, ln = lane & 15, n = nt * 16 + ln;
    bf16x8 o;
#pragma unroll
    for (int j = 0; j < 8; ++j) {
      int k = kb * 32 + q * 8 + j;
      o[j] = (k < 266) ? f2bf(Wg[k * 128 + n]) : (short)0;
    }
    Wgf[t] = o;
  }
}

// ---------------- fused 3-stage MLP ----------------
// Block: 512 thr = 8 waves (wr<2, wc<4); tile 128 rows x 512 cols.
// Stage1: barrier-free; A direct from x (reg prefetch + cvt_pk), B direct
//         from L2-resident fragment-ordered W1f.
// Handoff: h transposed through LDS in TWO 128x256 chunks (64 KB) so LDS
//          stays at 64 KB -> 2 blocks/CU -> 4 waves/SIMD (was 1 blk, 2 w/SIMD).
// Stage2 K-blocks remapped per chunk: kb2 = (k'>>1)*4 + c2*2 + (k'&1).
__global__ __launch_bounds__(512, 4) void mlp_k(
    const float* __restrict__ x, const bf16x8* __restrict__ W1f,
    const bf16x8* __restrict__ W2f, const bf16x8* __restrict__ Wgf,
    const float* __restrict__ b1, const float* __restrict__ b2,
    const float* __restrict__ dinv, unsigned short* __restrict__ y) {
  __shared__ __align__(16) short H[32768];  // 64 KB
  const int tid = threadIdx.x;
  const int wave = tid >> 6, lane = tid & 63;
  const int q = lane >> 4, ln = lane & 15;
  const int wr = wave >> 2, wc = wave & 3;
  int rb = blockIdx.x * 128;
  if (rb > NN - 128) rb = NN - 128;  // tail overlap: duplicate identical work

  // per-lane A row pointers (row = rb + wr*64 + mt*16 + ln, k-offset q*8)
  const float* xq[4];
#pragma unroll
  for (int mt = 0; mt < 4; ++mt)
    xq[mt] = x + (size_t)(rb + wr * 64 + mt * 16 + ln) * 1010 + q * 8;

  // ---- stage 1: h = relu(x[:, :1000] @ W1 + b1) ----
  f32x4 acc1[4][8];
#pragma unroll
  for (int a = 0; a < 4; ++a)
#pragma unroll
    for (int b = 0; b < 8; ++b) acc1[a][b] = f32x4{0.f, 0.f, 0.f, 0.f};

  // A prefetch buffer (8 floats per mt). Guard only matters for the final
  // K-block (cols can reach 1009/appear OOB on the last row): peeled into a
  // uniform kb==30 branch so the hot loop's prefetch is unguarded.
  float2 pa[4][4];
#pragma unroll
  for (int mt = 0; mt < 4; ++mt)
#pragma unroll
    for (int j = 0; j < 4; ++j) pa[mt][j] = *(const float2*)(xq[mt] + j * 2);

#pragma unroll 1
  for (int kb = 0; kb < 32; ++kb) {
    bf16x8 af[4];
#pragma unroll
    for (int mt = 0; mt < 4; ++mt) {
      union { unsigned u[4]; bf16x8 v; } c;
#pragma unroll
      for (int j = 0; j < 4; ++j) c.u[j] = cvtpk(pa[mt][j].x, pa[mt][j].y);
      af[mt] = c.v;
    }
    if (kb < 30) {  // unguarded prefetch: max col 991 < 1010, always in-bounds
#pragma unroll
      for (int mt = 0; mt < 4; ++mt)
#pragma unroll
        for (int j = 0; j < 4; ++j)
          pa[mt][j] = *(const float2*)(xq[mt] + (kb + 1) * 32 + j * 2);
    } else if (kb == 30) {  // guarded prefetch of final K-block (cols 992..1023)
      int base = 31 * 32 + q * 8;
#pragma unroll
      for (int mt = 0; mt < 4; ++mt)
#pragma unroll
        for (int j = 0; j < 4; ++j) {
          float2 t = {0.f, 0.f};
          if (base + j * 2 + 2 <= 1010)  // cols 1000..1009 load demo (W1f pad=0)
            t = *(const float2*)(xq[mt] + 31 * 32 + j * 2);
          pa[mt][j] = t;
        }
    }
    const bf16x8* wb = W1f + ((kb * 32 + wc * 8) * 64 + lane);
#pragma unroll
    for (int i = 0; i < 8; ++i) {
      bf16x8 bfv = wb[i * 64];
#pragma unroll
      for (int mt = 0; mt < 4; ++mt)
        acc1[mt][i] = __builtin_amdgcn_mfma_f32_16x16x32_bf16(af[mt], bfv, acc1[mt][i], 0, 0, 0);
    }
  }

  // ---- stage 2: subj = h @ W2 + b2, chunked 2x (128x256 h cols per chunk) ----
  // Chunk c2 holds writer-cols wc*128 + [c2*64, c2*64+64) for each wc, stored
  // at local col' = wc*64 + ii*16 + ln (ii = i - c2*4), row stride 256 shorts,
  // 16B-granule XOR swizzle g ^= (row&7).
  f32x4 acc2[4][4];
#pragma unroll
  for (int a = 0; a < 4; ++a)
#pragma unroll
    for (int b = 0; b < 4; ++b) acc2[a][b] = f32x4{0.f, 0.f, 0.f, 0.f};

#pragma unroll 1
  for (int c2 = 0; c2 < 2; ++c2) {
    if (c2) __syncthreads();  // prev chunk's reads complete before overwrite
    {
#pragma unroll
      for (int ii = 0; ii < 4; ++ii) {
        int i = c2 * 4 + ii;
        float bv = b1[wc * 128 + i * 16 + ln];
        int cc = wc * 64 + ii * 16 + ln;  // chunk-local column
#pragma unroll
        for (int mt = 0; mt < 4; ++mt)
#pragma unroll
          for (int r = 0; r < 4; ++r) {
            int rl = wr * 64 + mt * 16 + q * 4 + r;
            float v = fmaxf(acc1[mt][i][r] + bv, 0.f);
            H[rl * 256 + ((((cc >> 3) ^ (rl & 7)) << 3) | (cc & 7))] = f2bf(v);
          }
      }
    }
    __syncthreads();  // chunk ready
#pragma unroll 2
    for (int kk = 0; kk < 8; ++kk) {
      int kb2 = (kk >> 1) * 4 + c2 * 2 + (kk & 1);  // global K-block
      bf16x8 af[4];
#pragma unroll
      for (int mt = 0; mt < 4; ++mt) {
        int rl = wr * 64 + mt * 16 + ln;
        af[mt] = *(const bf16x8*)&H[rl * 256 + (((kk * 4 + q) ^ (rl & 7)) << 3)];
      }
      const bf16x8* wb = W2f + ((kb2 * 16 + wc * 4) * 64 + lane);
#pragma unroll
      for (int i = 0; i < 4; ++i) {
        bf16x8 bfv = wb[i * 64];
#pragma unroll
        for (int mt = 0; mt < 4; ++mt)
          acc2[mt][i] = __builtin_amdgcn_mfma_f32_16x16x32_bf16(af[mt], bfv, acc2[mt][i], 0, 0, 0);
      }
    }
  }
  __syncthreads();  // all stage-2 reads done; H reusable for subj

  // ---- handoff 2: subj (+b2, no relu) into SB (= H region, 64 KB) ----
  {
    float bv2[4];
#pragma unroll
    for (int i = 0; i < 4; ++i) bv2[i] = b2[wc * 64 + i * 16 + ln];
#pragma unroll
    for (int mt = 0; mt < 4; ++mt)
#pragma unroll
      for (int i = 0; i < 4; ++i) {
        int cc = wc * 64 + i * 16 + ln;
#pragma unroll
        for (int r = 0; r < 4; ++r) {
          int rl = wr * 64 + mt * 16 + q * 4 + r;
          H[rl * 256 + ((((cc >> 3) ^ (rl & 7)) << 3) | (cc & 7))] =
              f2bf(acc2[mt][i][r] + bv2[i]);
        }
      }
  }
  __syncthreads();  // SB ready

  // ---- stage 3: xt = subj @ Wg[0:256] + demo @ Wg[256:266] ----
  f32x4 acc3[4][2];
#pragma unroll
  for (int a = 0; a < 4; ++a)
#pragma unroll
    for (int b = 0; b < 2; ++b) acc3[a][b] = f32x4{0.f, 0.f, 0.f, 0.f};

#pragma unroll 2
  for (int k3 = 0; k3 < 8; ++k3) {
    bf16x8 af[4];
#pragma unroll
    for (int mt = 0; mt < 4; ++mt) {
      int rl = wr * 64 + mt * 16 + ln;
      af[mt] = *(const bf16x8*)&H[rl * 256 + (((k3 * 4 + q) ^ (rl & 7)) << 3)];
    }
    const bf16x8* wb = Wgf + ((k3 * 8 + wc * 2) * 64 + lane);
#pragma unroll
    for (int i = 0; i < 2; ++i) {
      bf16x8 bfv = wb[i * 64];
#pragma unroll
      for (int mt = 0; mt < 4; ++mt)
        acc3[mt][i] = __builtin_amdgcn_mfma_f32_16x16x32_bf16(af[mt], bfv, acc3[mt][i], 0, 0, 0);
    }
  }
  {  // demo K-block (kb3 = 8): A from x demo cols directly (guarded loads)
    bf16x8 af[4];
#pragma unroll
    for (int mt = 0; mt < 4; ++mt) {
      union { unsigned u[4]; bf16x8 v; } c;
#pragma unroll
      for (int j = 0; j < 8; j += 2) {
        float f0 = (q * 8 + j < 10) ? xq[mt][1000 + j] : 0.f;
        float f1 = (q * 8 + j + 1 < 10) ? xq[mt][1001 + j] : 0.f;
        c.u[j >> 1] = cvtpk(f0, f1);
      }
      af[mt] = c.v;
    }
    const bf16x8* wb = Wgf + ((8 * 8 + wc * 2) * 64 + lane);
#pragma unroll
    for (int i = 0; i < 2; ++i) {
      bf16x8 bfv = wb[i * 64];
#pragma unroll
      for (int mt = 0; mt < 4; ++mt)
        acc3[mt][i] = __builtin_amdgcn_mfma_f32_16x16x32_bf16(af[mt], bfv, acc3[mt][i], 0, 0, 0);
    }
  }

  // ---- epilogue: y[node][col] = bf16(xt * dinv[node]) ----
#pragma unroll
  for (int mt = 0; mt < 4; ++mt) {
    float dv[4];
#pragma unroll
    for (int r = 0; r < 4; ++r) dv[r] = dinv[rb + wr * 64 + mt * 16 + q * 4 + r];
#pragma unroll
    for (int i = 0; i < 2; ++i)
#pragma unroll
      for (int r = 0; r < 4; ++r) {
        int node = rb + wr * 64 + mt * 16 + q * 4 + r;
        y[(size_t)node * 128 + wc * 32 + i * 16 + ln] =
            (unsigned short)f2bf(acc3[mt][i][r] * dv[r]);
      }
  }
}

// ---------------- graph: degree count (edge_index arrives as int32) --------
__global__ void deg_k(const int* __restrict__ ei, int* __restrict__ deg) {
  int i = blockIdx.x * 256 + threadIdx.x;
  if (i < NE) {
    unsigned d = (unsigned)ei[NE + i];
    if (d < (unsigned)NN) atomicAdd(&deg[d], 1);
  }
}

// ---------------- 3-phase parallel scan (100 blocks x 1000 nodes) ----------
__global__ void sc1_k(const int* __restrict__ deg, int* __restrict__ btot) {
  __shared__ int red[4];
  int b = blockIdx.x, t = threadIdx.x;
  int s = 0;
  for (int i = t; i < 1000; i += 256) s += deg[b * 1000 + i];
  s += __shfl_down(s, 32); s += __shfl_down(s, 16); s += __shfl_down(s, 8);
  s += __shfl_down(s, 4);  s += __shfl_down(s, 2);  s += __shfl_down(s, 1);
  if ((t & 63) == 0) red[t >> 6] = s;
  __syncthreads();
  if (t == 0) btot[b] = red[0] + red[1] + red[2] + red[3];
}

__global__ void sc2_k(const int* __restrict__ btot, int* __restrict__ boff,
                      int* __restrict__ row_ptr) {
  __shared__ int wt[2];
  int t = threadIdx.x;  // 128
  int xv = (t < 100) ? btot[t] : 0;
  int inc = xv;
  for (int d = 1; d < 64; d <<= 1) {
    int o = __shfl_up(inc, d);
    if ((t & 63) >= d) inc += o;
  }
  if ((t & 63) == 63) wt[t >> 6] = inc;
  __syncthreads();
  if (t >= 64) inc += wt[0];
  if (t < 100) boff[t] = inc - xv;
  if (t == 99) row_ptr[NN] = inc;
}

__global__ void sc3_k(const int* __restrict__ deg, const int* __restrict__ boff,
                      int* __restrict__ row_ptr, int* __restrict__ cursor,
                      float* __restrict__ dinv) {
  __shared__ int part[256];
  int b = blockIdx.x, t = threadIdx.x;
  int i0 = t * 4;
  int d[4]; int s = 0;
#pragma unroll
  for (int j = 0; j < 4; ++j) {
    int i = i0 + j;
    d[j] = (i < 1000) ? deg[b * 1000 + i] : 0;
    s += d[j];
  }
  part[t] = s;
  __syncthreads();
  int val = s;
  for (int off = 1; off < 256; off <<= 1) {
    int add = (t >= off) ? part[t - off] : 0;
    __syncthreads();
    val += add;
    part[t] = val;
    __syncthreads();
  }
  int run = boff[b] + val - s;
#pragma unroll
  for (int j = 0; j < 4; ++j) {
    int i = i0 + j;
    if (i < 1000) {
      int node = b * 1000 + i;
      row_ptr[node] = run;
      cursor[node] = run;
      dinv[node] = rsqrtf((float)(d[j] + 1));
      run += d[j];
    }
  }
}

// ---------------- CSR fill ----------------
__global__ void fill_k(const int* __restrict__ ei, int* __restrict__ cursor,
                       int* __restrict__ csr) {
  int i = blockIdx.x * 256 + threadIdx.x;
  if (i < NE) {
    unsigned s = (unsigned)ei[i];
    unsigned d = (unsigned)ei[NE + i];
    if (d < (unsigned)NN && s < (unsigned)NN) {
      unsigned pos = (unsigned)atomicAdd(&cursor[d], 1);
      if (pos < (unsigned)NE) csr[pos] = (int)s;
    }
  }
}

// -------- aggregate + relu + dot(Wo) per node (1 wave/node, 4 nodes/block) --
// Inner gather unrolled x8: 8 independent row loads in flight per waitcnt.
__global__ void agg_k(const unsigned short* __restrict__ y,
                      const int* __restrict__ row_ptr, const int* __restrict__ csr,
                      const float* __restrict__ dinv, const float* __restrict__ bg,
                      const float* __restrict__ Wo, float* __restrict__ c) {
  int w = threadIdx.x >> 6, l = threadIdx.x & 63;
  int n = blockIdx.x * 4 + w;  // NN = 25000*4 exact
  unsigned u = ((const unsigned*)(y + (size_t)n * 128))[l];  // self-loop
  float a0 = bf2f((unsigned short)(u & 0xFFFF));
  float a1 = bf2f((unsigned short)(u >> 16));
  int e0 = row_ptr[n], e1 = row_ptr[n + 1];
  for (int e = e0; e < e1; e += 64) {
    int sv = (e + l < e1) ? csr[e + l] : 0;  // lane-parallel prefetch
    int m = e1 - e; if (m > 64) m = 64;
    int j = 0;
    for (; j + 8 <= m; j += 8) {
      unsigned v[8];
#pragma unroll
      for (int u8 = 0; u8 < 8; ++u8) {
        int s = __shfl(sv, j + u8);
        v[u8] = ((const unsigned*)(y + (size_t)s * 128))[l];
      }
#pragma unroll
      for (int u8 = 0; u8 < 8; ++u8) {
        a0 += bf2f((unsigned short)(v[u8] & 0xFFFF));
        a1 += bf2f((unsigned short)(v[u8] >> 16));
      }
    }
    for (; j < m; ++j) {
      int s = __shfl(sv, j);
      unsigned v = ((const unsigned*)(y + (size_t)s * 128))[l];
      a0 += bf2f((unsigned short)(v & 0xFFFF));
      a1 += bf2f((unsigned short)(v >> 16));
    }
  }
  float dn = dinv[n];
  float2 bg2 = ((const float2*)bg)[l];
  float2 wo2 = ((const float2*)Wo)[l];
  float v = fmaxf(a0 * dn + bg2.x, 0.f) * wo2.x + fmaxf(a1 * dn + bg2.y, 0.f) * wo2.y;
  v += __shfl_down(v, 32); v += __shfl_down(v, 16); v += __shfl_down(v, 8);
  v += __shfl_down(v, 4);  v += __shfl_down(v, 2);  v += __shfl_down(v, 1);
  if (l == 0) c[n] = v;
}

// ---------------- final mean + bo ----------------
__global__ void red_k(const float* __restrict__ c, const float* __restrict__ bo,
                      float* __restrict__ out) {
  int t = threadIdx.x;
  float s = 0.f;
  for (int i = t; i < NN; i += 1024) s += c[i];
  s += __shfl_down(s, 32); s += __shfl_down(s, 16); s += __shfl_down(s, 8);
  s += __shfl_down(s, 4);  s += __shfl_down(s, 2);  s += __shfl_down(s, 1);
  __shared__ float red[16];
  if ((t & 63) == 0) red[t >> 6] = s;
  __syncthreads();
  if (t == 0) {
    float tot = 0.f;
    for (int w = 0; w < 16; ++w) tot += red[w];
    out[0] = tot / (float)NN + bo[0];
  }
}

extern "C" void kernel_launch(void* const* d_in, const int* in_sizes, int n_in,
                              void* d_out, int out_size, void* d_ws, size_t ws_size,
                              hipStream_t stream) {
  (void)in_sizes; (void)n_in; (void)out_size; (void)ws_size;
  const float* x  = (const float*)d_in[0];
  const int*   ei = (const int*)d_in[1];  // int32 from harness
  const float* W1 = (const float*)d_in[2];
  const float* b1 = (const float*)d_in[3];
  const float* W2 = (const float*)d_in[4];
  const float* b2 = (const float*)d_in[5];
  const float* Wg = (const float*)d_in[6];
  const float* bg = (const float*)d_in[7];
  const float* Wo = (const float*)d_in[8];
  const float* bo = (const float*)d_in[9];
  float* out = (float*)d_out;

  char* ws = (char*)d_ws;
  size_t off = 0;
  auto alloc = [&](size_t bytes) -> void* {
    void* p = ws + off;
    off = (off + bytes + 255) & ~(size_t)255;
    return p;
  };
  bf16x8* W1f = (bf16x8*)alloc((size_t)32 * 32 * 64 * 16);  // 1 MB
  bf16x8* W2f = (bf16x8*)alloc((size_t)16 * 16 * 64 * 16);  // 256 KB
  bf16x8* Wgf = (bf16x8*)alloc((size_t)9 * 8 * 64 * 16);    // 72 KB
  int*    deg  = (int*)alloc((size_t)NN * 4);
  float*  dinv = (float*)alloc((size_t)NN * 4);
  int*    rowp = (int*)alloc((size_t)(NN + 1) * 4);
  int*    curs = (int*)alloc((size_t)NN * 4);
  float*  carr = (float*)alloc((size_t)NN * 4);
  int*    btot = (int*)alloc((size_t)128 * 4);
  int*    boff = (int*)alloc((size_t)128 * 4);
  int*    csr  = (int*)alloc((size_t)NE * 4);               // 6.4 MB
  unsigned short* y = (unsigned short*)alloc((size_t)NN * 128 * 2);  // 25.6 MB

  zero_k<<<(NN + 255) / 256, 256, 0, stream>>>(deg, NN);
  wconv_k<<<338, 256, 0, stream>>>(W1, W2, Wg, W1f, W2f, Wgf);
  deg_k<<<(NE + 255) / 256, 256, 0, stream>>>(ei, deg);
  sc1_k<<<100, 256, 0, stream>>>(deg, btot);
  sc2_k<<<1, 128, 0, stream>>>(btot, boff, rowp);
  sc3_k<<<100, 256, 0, stream>>>(deg, boff, rowp, curs, dinv);
  fill_k<<<(NE + 255) / 256, 256, 0, stream>>>(ei, curs, csr);
  mlp_k<<<782, 512, 0, stream>>>(x, W1f, W2f, Wgf, b1, b2, dinv, y);
  agg_k<<<25000, 256, 0, stream>>>(y, rowp, csr, dinv, bg, Wo, carr);
  red_k<<<1, 1024, 0, stream>>>(carr, bo, out);
}

// Round 4
// 1147.493 us; speedup vs baseline: 2.4358x; 2.4358x over previous
//
#include <hip/hip_runtime.h>
#include <cstdint>

#define NN 100000
#define NE 1600000

typedef __attribute__((ext_vector_type(8))) short bf16x8;
typedef __attribute__((ext_vector_type(4))) float f32x4;

static __device__ __forceinline__ short f2bf(float f) {
  union { float f; unsigned u; } v; v.f = f;
  unsigned r = (v.u + 0x7FFFu + ((v.u >> 16) & 1u)) >> 16;
  return (short)r;
}
static __device__ __forceinline__ float bf2f(unsigned short s) {
  union { unsigned u; float f; } v; v.u = ((unsigned)s) << 16;
  return v.f;
}
// pack 2 f32 -> 2 bf16 in one dword (RTNE), dst[15:0]=lo, dst[31:16]=hi
static __device__ __forceinline__ unsigned cvtpk(float lo, float hi) {
  unsigned r;
  asm("v_cvt_pk_bf16_f32 %0, %1, %2" : "=v"(r) : "v"(lo), "v"(hi));
  return r;
}

// ---------------- zero helper ----------------
__global__ void zero_k(int* __restrict__ p, int n) {
  int i = blockIdx.x * 256 + threadIdx.x;
  if (i < n) p[i] = 0;
}

// ---------------- weight pre-convert to MFMA fragment order ----------------
// W1f: [kb<32][nt<32][lane<64][j<8]  K=1024(pad 1000), N=512   (1 MB)
// W2f: [kb<16][nt<16][lane][j]       K=512, N=256              (256KB)
// Wgf: [kb<9 ][nt<8 ][lane][j]       K=288(pad 266), N=128     (72KB)
__global__ void wconv_k(const float* __restrict__ W1, const float* __restrict__ W2,
                        const float* __restrict__ Wg,
                        bf16x8* __restrict__ W1f, bf16x8* __restrict__ W2f,
                        bf16x8* __restrict__ Wgf) {
  int id = blockIdx.x * 256 + threadIdx.x;
  const int n1 = 32 * 32 * 64, n2 = 16 * 16 * 64, n3 = 9 * 8 * 64;
  if (id < n1) {
    int lane = id & 63, nt = (id >> 6) & 31, kb = id >> 11;
    int q = lane >> 4, ln = lane & 15, n = nt * 16 + ln;
    bf16x8 o;
#pragma unroll
    for (int j = 0; j < 8; ++j) {
      int k = kb * 32 + q * 8 + j;
      o[j] = (k < 1000) ? f2bf(W1[k * 512 + n]) : (short)0;
    }
    W1f[id] = o;
  } else if (id < n1 + n2) {
    int t = id - n1;
    int lane = t & 63, nt = (t >> 6) & 15, kb = t >> 10;
    int q = lane >> 4, ln = lane & 15, n = nt * 16 + ln;
    bf16x8 o;
#pragma unroll
    for (int j = 0; j < 8; ++j) {
      int k = kb * 32 + q * 8 + j;
      o[j] = f2bf(W2[k * 256 + n]);
    }
    W2f[t] = o;
  } else if (id < n1 + n2 + n3) {
    int t = id - n1 - n2;
    int lane = t & 63, nt = (t >> 6) & 7, kb = t >> 9;
    int q = lane >> 4, ln = lane & 15, n = nt * 16 + ln;
    bf16x8 o;
#pragma unroll
    for (int j = 0; j < 8; ++j) {
      int k = kb * 32 + q * 8 + j;
      o[j] = (k < 266) ? f2bf(Wg[k * 128 + n]) : (short)0;
    }
    Wgf[t] = o;
  }
}

// ---------------- fused 3-stage MLP ----------------
// Block: 512 thr = 8 waves; tile 64 rows x 512 cols. Each wave owns
// 64 rows x 64 cols in stage 1 (acc1 = 64 regs, half of the 128-row variant)
// so the live set fits ~128 regs -> HW can co-schedule 2 blocks/CU with the
// 64 KB LDS H-buffer. NO forced register cap (launch_bounds min-waves=2):
// worst case is 1 blk/CU (round-2 behavior), spills impossible by design.
// Stage1 barrier-free (A reg-prefetch from x, B direct from L2-resident W1f);
// 3 barriers total for the two LDS handoffs.
__global__ __launch_bounds__(512, 2) void mlp_k(
    const float* __restrict__ x, const bf16x8* __restrict__ W1f,
    const bf16x8* __restrict__ W2f, const bf16x8* __restrict__ Wgf,
    const float* __restrict__ b1, const float* __restrict__ b2,
    const float* __restrict__ dinv, unsigned short* __restrict__ y) {
  __shared__ __align__(16) short H[32768];  // 64 KB
  const int tid = threadIdx.x;
  const int wc = tid >> 6, lane = tid & 63;  // wc = wave 0..7 (column group)
  const int q = lane >> 4, ln = lane & 15;
  int rb = blockIdx.x * 64;
  if (rb > NN - 64) rb = NN - 64;  // tail overlap: duplicate identical work

  // per-lane A row pointers (row = rb + mt*16 + ln, k-offset q*8)
  const float* xq[4];
#pragma unroll
  for (int mt = 0; mt < 4; ++mt)
    xq[mt] = x + (size_t)(rb + mt * 16 + ln) * 1010 + q * 8;

  // ---- stage 1: h = relu(x[:, :1000] @ W1 + b1); wave cols wc*64..+64 ----
  f32x4 acc1[4][4];
#pragma unroll
  for (int a = 0; a < 4; ++a)
#pragma unroll
    for (int b = 0; b < 4; ++b) acc1[a][b] = f32x4{0.f, 0.f, 0.f, 0.f};

  float2 pa[4][4];
#pragma unroll
  for (int mt = 0; mt < 4; ++mt)
#pragma unroll
    for (int j = 0; j < 4; ++j) pa[mt][j] = *(const float2*)(xq[mt] + j * 2);

#pragma unroll 1
  for (int kb = 0; kb < 32; ++kb) {
    bf16x8 af[4];
#pragma unroll
    for (int mt = 0; mt < 4; ++mt) {
      union { unsigned u[4]; bf16x8 v; } c;
#pragma unroll
      for (int j = 0; j < 4; ++j) c.u[j] = cvtpk(pa[mt][j].x, pa[mt][j].y);
      af[mt] = c.v;
    }
    if (kb < 30) {  // unguarded prefetch: max col 991 < 1010, always in-bounds
#pragma unroll
      for (int mt = 0; mt < 4; ++mt)
#pragma unroll
        for (int j = 0; j < 4; ++j)
          pa[mt][j] = *(const float2*)(xq[mt] + (kb + 1) * 32 + j * 2);
    } else if (kb == 30) {  // guarded prefetch of final K-block (cols 992..1023)
      int base = 31 * 32 + q * 8;
#pragma unroll
      for (int mt = 0; mt < 4; ++mt)
#pragma unroll
        for (int j = 0; j < 4; ++j) {
          float2 t = {0.f, 0.f};
          if (base + j * 2 + 2 <= 1010)  // cols 1000..1009 load demo (W1f pad=0)
            t = *(const float2*)(xq[mt] + 31 * 32 + j * 2);
          pa[mt][j] = t;
        }
    }
    const bf16x8* wb = W1f + ((kb * 32 + wc * 4) * 64 + lane);
#pragma unroll
    for (int i = 0; i < 4; ++i) {
      bf16x8 bfv = wb[i * 64];
#pragma unroll
      for (int mt = 0; mt < 4; ++mt)
        acc1[mt][i] = __builtin_amdgcn_mfma_f32_16x16x32_bf16(af[mt], bfv, acc1[mt][i], 0, 0, 0);
    }
  }

  // ---- handoff 1: h (bias+relu) into H [64 rows][512 cols bf16] ----
  // 16B granule g = cc>>3 swizzled g ^= (rl&7).
  {
#pragma unroll
    for (int i = 0; i < 4; ++i) {
      float bv = b1[wc * 64 + i * 16 + ln];
      int cc = wc * 64 + i * 16 + ln;
#pragma unroll
      for (int mt = 0; mt < 4; ++mt)
#pragma unroll
        for (int r = 0; r < 4; ++r) {
          int rl = mt * 16 + q * 4 + r;
          float v = fmaxf(acc1[mt][i][r] + bv, 0.f);
          H[rl * 512 + ((((cc >> 3) ^ (rl & 7)) << 3) | (cc & 7))] = f2bf(v);
        }
    }
  }
  __syncthreads();  // barrier 1: H ready; acc1 dead from here

  // ---- stage 2: subj = h @ W2 + b2; wave cols wc*32..+32 ----
  f32x4 acc2[4][2];
#pragma unroll
  for (int a = 0; a < 4; ++a)
#pragma unroll
    for (int b = 0; b < 2; ++b) acc2[a][b] = f32x4{0.f, 0.f, 0.f, 0.f};

#pragma unroll 2
  for (int k2 = 0; k2 < 16; ++k2) {
    bf16x8 af[4];
#pragma unroll
    for (int mt = 0; mt < 4; ++mt) {
      int rl = mt * 16 + ln;
      af[mt] = *(const bf16x8*)&H[rl * 512 + (((k2 * 4 + q) ^ (rl & 7)) << 3)];
    }
    const bf16x8* wb = W2f + ((k2 * 16 + wc * 2) * 64 + lane);
#pragma unroll
    for (int i = 0; i < 2; ++i) {
      bf16x8 bfv = wb[i * 64];
#pragma unroll
      for (int mt = 0; mt < 4; ++mt)
        acc2[mt][i] = __builtin_amdgcn_mfma_f32_16x16x32_bf16(af[mt], bfv, acc2[mt][i], 0, 0, 0);
    }
  }
  __syncthreads();  // barrier 2: all H reads done, region reusable

  // ---- handoff 2: subj (+b2) into SB = H region [64 rows][256 cols] ----
  {
#pragma unroll
    for (int i = 0; i < 2; ++i) {
      float bv2 = b2[wc * 32 + i * 16 + ln];
      int cc = wc * 32 + i * 16 + ln;
#pragma unroll
      for (int mt = 0; mt < 4; ++mt)
#pragma unroll
        for (int r = 0; r < 4; ++r) {
          int rl = mt * 16 + q * 4 + r;
          H[rl * 256 + ((((cc >> 3) ^ (rl & 7)) << 3) | (cc & 7))] =
              f2bf(acc2[mt][i][r] + bv2);
        }
    }
  }
  __syncthreads();  // barrier 3: SB ready

  // ---- stage 3: xt = subj @ Wg[0:256] + demo @ Wg[256:266]; wave col grp wc ----
  f32x4 acc3[4];
#pragma unroll
  for (int a = 0; a < 4; ++a) acc3[a] = f32x4{0.f, 0.f, 0.f, 0.f};

#pragma unroll 2
  for (int k3 = 0; k3 < 8; ++k3) {
    bf16x8 af[4];
#pragma unroll
    for (int mt = 0; mt < 4; ++mt) {
      int rl = mt * 16 + ln;
      af[mt] = *(const bf16x8*)&H[rl * 256 + (((k3 * 4 + q) ^ (rl & 7)) << 3)];
    }
    bf16x8 bfv = Wgf[(k3 * 8 + wc) * 64 + lane];
#pragma unroll
    for (int mt = 0; mt < 4; ++mt)
      acc3[mt] = __builtin_amdgcn_mfma_f32_16x16x32_bf16(af[mt], bfv, acc3[mt], 0, 0, 0);
  }
  {  // demo K-block (kb3 = 8): A from x demo cols directly (guarded loads)
    bf16x8 af[4];
#pragma unroll
    for (int mt = 0; mt < 4; ++mt) {
      const float* xr2 = x + (size_t)(rb + mt * 16 + ln) * 1010 + 1000;
      union { unsigned u[4]; bf16x8 v; } c;
#pragma unroll
      for (int j = 0; j < 8; j += 2) {
        float f0 = (q * 8 + j < 10) ? xr2[q * 8 + j] : 0.f;
        float f1 = (q * 8 + j + 1 < 10) ? xr2[q * 8 + j + 1] : 0.f;
        c.u[j >> 1] = cvtpk(f0, f1);
      }
      af[mt] = c.v;
    }
    bf16x8 bfv = Wgf[(64 + wc) * 64 + lane];
#pragma unroll
    for (int mt = 0; mt < 4; ++mt)
      acc3[mt] = __builtin_amdgcn_mfma_f32_16x16x32_bf16(af[mt], bfv, acc3[mt], 0, 0, 0);
  }

  // ---- epilogue: y[node][col] = bf16(xt * dinv[node]); wave cols wc*16+ln ----
#pragma unroll
  for (int mt = 0; mt < 4; ++mt) {
#pragma unroll
    for (int r = 0; r < 4; ++r) {
      int node = rb + mt * 16 + q * 4 + r;
      float dv = dinv[node];
      y[(size_t)node * 128 + wc * 16 + ln] =
          (unsigned short)f2bf(acc3[mt][r] * dv);
    }
  }
}

// ---------------- graph: degree count (edge_index arrives as int32) --------
__global__ void deg_k(const int* __restrict__ ei, int* __restrict__ deg) {
  int i = blockIdx.x * 256 + threadIdx.x;
  if (i < NE) {
    unsigned d = (unsigned)ei[NE + i];
    if (d < (unsigned)NN) atomicAdd(&deg[d], 1);
  }
}

// ---------------- 3-phase parallel scan (100 blocks x 1000 nodes) ----------
__global__ void sc1_k(const int* __restrict__ deg, int* __restrict__ btot) {
  __shared__ int red[4];
  int b = blockIdx.x, t = threadIdx.x;
  int s = 0;
  for (int i = t; i < 1000; i += 256) s += deg[b * 1000 + i];
  s += __shfl_down(s, 32); s += __shfl_down(s, 16); s += __shfl_down(s, 8);
  s += __shfl_down(s, 4);  s += __shfl_down(s, 2);  s += __shfl_down(s, 1);
  if ((t & 63) == 0) red[t >> 6] = s;
  __syncthreads();
  if (t == 0) btot[b] = red[0] + red[1] + red[2] + red[3];
}

__global__ void sc2_k(const int* __restrict__ btot, int* __restrict__ boff,
                      int* __restrict__ row_ptr) {
  __shared__ int wt[2];
  int t = threadIdx.x;  // 128
  int xv = (t < 100) ? btot[t] : 0;
  int inc = xv;
  for (int d = 1; d < 64; d <<= 1) {
    int o = __shfl_up(inc, d);
    if ((t & 63) >= d) inc += o;
  }
  if ((t & 63) == 63) wt[t >> 6] = inc;
  __syncthreads();
  if (t >= 64) inc += wt[0];
  if (t < 100) boff[t] = inc - xv;
  if (t == 99) row_ptr[NN] = inc;
}

__global__ void sc3_k(const int* __restrict__ deg, const int* __restrict__ boff,
                      int* __restrict__ row_ptr, int* __restrict__ cursor,
                      float* __restrict__ dinv) {
  __shared__ int part[256];
  int b = blockIdx.x, t = threadIdx.x;
  int i0 = t * 4;
  int d[4]; int s = 0;
#pragma unroll
  for (int j = 0; j < 4; ++j) {
    int i = i0 + j;
    d[j] = (i < 1000) ? deg[b * 1000 + i] : 0;
    s += d[j];
  }
  part[t] = s;
  __syncthreads();
  int val = s;
  for (int off = 1; off < 256; off <<= 1) {
    int add = (t >= off) ? part[t - off] : 0;
    __syncthreads();
    val += add;
    part[t] = val;
    __syncthreads();
  }
  int run = boff[b] + val - s;
#pragma unroll
  for (int j = 0; j < 4; ++j) {
    int i = i0 + j;
    if (i < 1000) {
      int node = b * 1000 + i;
      row_ptr[node] = run;
      cursor[node] = run;
      dinv[node] = rsqrtf((float)(d[j] + 1));
      run += d[j];
    }
  }
}

// ---------------- CSR fill ----------------
__global__ void fill_k(const int* __restrict__ ei, int* __restrict__ cursor,
                       int* __restrict__ csr) {
  int i = blockIdx.x * 256 + threadIdx.x;
  if (i < NE) {
    unsigned s = (unsigned)ei[i];
    unsigned d = (unsigned)ei[NE + i];
    if (d < (unsigned)NN && s < (unsigned)NN) {
      unsigned pos = (unsigned)atomicAdd(&cursor[d], 1);
      if (pos < (unsigned)NE) csr[pos] = (int)s;
    }
  }
}

// -------- aggregate + relu + dot(Wo) per node (1 wave/node, 4 nodes/block) --
// Inner gather unrolled x8: 8 independent row loads in flight per waitcnt.
__global__ void agg_k(const unsigned short* __restrict__ y,
                      const int* __restrict__ row_ptr, const int* __restrict__ csr,
                      const float* __restrict__ dinv, const float* __restrict__ bg,
                      const float* __restrict__ Wo, float* __restrict__ c) {
  int w = threadIdx.x >> 6, l = threadIdx.x & 63;
  int n = blockIdx.x * 4 + w;  // NN = 25000*4 exact
  unsigned u = ((const unsigned*)(y + (size_t)n * 128))[l];  // self-loop
  float a0 = bf2f((unsigned short)(u & 0xFFFF));
  float a1 = bf2f((unsigned short)(u >> 16));
  int e0 = row_ptr[n], e1 = row_ptr[n + 1];
  for (int e = e0; e < e1; e += 64) {
    int sv = (e + l < e1) ? csr[e + l] : 0;  // lane-parallel prefetch
    int m = e1 - e; if (m > 64) m = 64;
    int j = 0;
    for (; j + 8 <= m; j += 8) {
      unsigned v[8];
#pragma unroll
      for (int u8 = 0; u8 < 8; ++u8) {
        int s = __shfl(sv, j + u8);
        v[u8] = ((const unsigned*)(y + (size_t)s * 128))[l];
      }
#pragma unroll
      for (int u8 = 0; u8 < 8; ++u8) {
        a0 += bf2f((unsigned short)(v[u8] & 0xFFFF));
        a1 += bf2f((unsigned short)(v[u8] >> 16));
      }
    }
    for (; j < m; ++j) {
      int s = __shfl(sv, j);
      unsigned v = ((const unsigned*)(y + (size_t)s * 128))[l];
      a0 += bf2f((unsigned short)(v & 0xFFFF));
      a1 += bf2f((unsigned short)(v >> 16));
    }
  }
  float dn = dinv[n];
  float2 bg2 = ((const float2*)bg)[l];
  float2 wo2 = ((const float2*)Wo)[l];
  float v = fmaxf(a0 * dn + bg2.x, 0.f) * wo2.x + fmaxf(a1 * dn + bg2.y, 0.f) * wo2.y;
  v += __shfl_down(v, 32); v += __shfl_down(v, 16); v += __shfl_down(v, 8);
  v += __shfl_down(v, 4);  v += __shfl_down(v, 2);  v += __shfl_down(v, 1);
  if (l == 0) c[n] = v;
}

// ---------------- final mean + bo ----------------
__global__ void red_k(const float* __restrict__ c, const float* __restrict__ bo,
                      float* __restrict__ out) {
  int t = threadIdx.x;
  float s = 0.f;
  for (int i = t; i < NN; i += 1024) s += c[i];
  s += __shfl_down(s, 32); s += __shfl_down(s, 16); s += __shfl_down(s, 8);
  s += __shfl_down(s, 4);  s += __shfl_down(s, 2);  s += __shfl_down(s, 1);
  __shared__ float red[16];
  if ((t & 63) == 0) red[t >> 6] = s;
  __syncthreads();
  if (t == 0) {
    float tot = 0.f;
    for (int w = 0; w < 16; ++w) tot += red[w];
    out[0] = tot / (float)NN + bo[0];
  }
}

extern "C" void kernel_launch(void* const* d_in, const int* in_sizes, int n_in,
                              void* d_out, int out_size, void* d_ws, size_t ws_size,
                              hipStream_t stream) {
  (void)in_sizes; (void)n_in; (void)out_size; (void)ws_size;
  const float* x  = (const float*)d_in[0];
  const int*   ei = (const int*)d_in[1];  // int32 from harness
  const float* W1 = (const float*)d_in[2];
  const float* b1 = (const float*)d_in[3];
  const float* W2 = (const float*)d_in[4];
  const float* b2 = (const float*)d_in[5];
  const float* Wg = (const float*)d_in[6];
  const float* bg = (const float*)d_in[7];
  const float* Wo = (const float*)d_in[8];
  const float* bo = (const float*)d_in[9];
  float* out = (float*)d_out;

  char* ws = (char*)d_ws;
  size_t off = 0;
  auto alloc = [&](size_t bytes) -> void* {
    void* p = ws + off;
    off = (off + bytes + 255) & ~(size_t)255;
    return p;
  };
  bf16x8* W1f = (bf16x8*)alloc((size_t)32 * 32 * 64 * 16);  // 1 MB
  bf16x8* W2f = (bf16x8*)alloc((size_t)16 * 16 * 64 * 16);  // 256 KB
  bf16x8* Wgf = (bf16x8*)alloc((size_t)9 * 8 * 64 * 16);    // 72 KB
  int*    deg  = (int*)alloc((size_t)NN * 4);
  float*  dinv = (float*)alloc((size_t)NN * 4);
  int*    rowp = (int*)alloc((size_t)(NN + 1) * 4);
  int*    curs = (int*)alloc((size_t)NN * 4);
  float*  carr = (float*)alloc((size_t)NN * 4);
  int*    btot = (int*)alloc((size_t)128 * 4);
  int*    boff = (int*)alloc((size_t)128 * 4);
  int*    csr  = (int*)alloc((size_t)NE * 4);               // 6.4 MB
  unsigned short* y = (unsigned short*)alloc((size_t)NN * 128 * 2);  // 25.6 MB

  zero_k<<<(NN + 255) / 256, 256, 0, stream>>>(deg, NN);
  wconv_k<<<338, 256, 0, stream>>>(W1, W2, Wg, W1f, W2f, Wgf);
  deg_k<<<(NE + 255) / 256, 256, 0, stream>>>(ei, deg);
  sc1_k<<<100, 256, 0, stream>>>(deg, btot);
  sc2_k<<<1, 128, 0, stream>>>(btot, boff, rowp);
  sc3_k<<<100, 256, 0, stream>>>(deg, boff, rowp, curs, dinv);
  fill_k<<<(NE + 255) / 256, 256, 0, stream>>>(ei, curs, csr);
  mlp_k<<<1563, 512, 0, stream>>>(x, W1f, W2f, Wgf, b1, b2, dinv, y);
  agg_k<<<25000, 256, 0, stream>>>(y, rowp, csr, dinv, bg, Wo, carr);
  red_k<<<1, 1024, 0, stream>>>(carr, bo, out);
}